// Round 14
// baseline (40847.049 us; speedup 1.0000x reference)
//
#include <hip/hip_runtime.h>
#include <math.h>

#define TT 8192
#define DD 1024
#define LWG 64    // WGs per layer
#define NWG 128   // total
#define TPB 512   // 8 waves; each wave owns 2 pre-rows + 4 U-rows
#define GCAP (1 << 15)

typedef __attribute__((ext_vector_type(2))) float f32x2;
typedef __attribute__((ext_vector_type(4))) float f32x4;

// ---- LLC-coherent (cross-XCD) accesses: sc0 sc1 ----
__device__ __forceinline__ void vdrain() { asm volatile("s_waitcnt vmcnt(0)" ::: "memory"); }
__device__ __forceinline__ void st4_x(float* p, f32x4 v) {
  asm volatile("global_store_dwordx4 %0, %1, off sc0 sc1" :: "v"(p), "v"(v) : "memory");
}
__device__ __forceinline__ void stu_x(unsigned* p, unsigned v) {
  asm volatile("global_store_dword %0, %1, off sc0 sc1" :: "v"(p), "v"(v) : "memory");
}
__device__ __forceinline__ f32x4 ld4_x(const float* p) {
  f32x4 r;
  asm volatile("global_load_dwordx4 %0, %1, off sc0 sc1\n\ts_waitcnt vmcnt(0)"
               : "=&v"(r) : "v"(p) : "memory");
  return r;
}
__device__ __forceinline__ void ld4_x2(const float* p0, const float* p1, f32x4& a, f32x4& b) {
  asm volatile("global_load_dwordx4 %0, %2, off sc0 sc1\n\t"
               "global_load_dwordx4 %1, %3, off sc0 sc1\n\t"
               "s_waitcnt vmcnt(0)"
               : "=&v"(a), "=&v"(b) : "v"(p0), "v"(p1) : "memory");
}
__device__ __forceinline__ void ld4_x3(const float* p0, const float* p1, const float* p2,
                                       f32x4& a, f32x4& b, f32x4& c) {
  asm volatile("global_load_dwordx4 %0, %3, off sc0 sc1\n\t"
               "global_load_dwordx4 %1, %4, off sc0 sc1\n\t"
               "global_load_dwordx4 %2, %5, off sc0 sc1\n\t"
               "s_waitcnt vmcnt(0)"
               : "=&v"(a), "=&v"(b), "=&v"(c) : "v"(p0), "v"(p1), "v"(p2) : "memory");
}
__device__ __forceinline__ unsigned ldu_x(const unsigned* p) {
  unsigned r;
  asm volatile("global_load_dword %0, %1, off sc0 sc1\n\ts_waitcnt vmcnt(0)"
               : "=&v"(r) : "v"(p) : "memory");
  return r;
}

// Epoch-tuple polls: one aligned 16B tuple {v0, v1, epoch, pad} — a single
// dwordx4 store is one LLC transaction, so flag and data arrive atomically.
// Hot-poll first 16 rounds (no sleep), then back off; abort => fast failure.
__device__ __forceinline__ f32x4 pollep(const float* p, float epf, unsigned* abortf) {
  int g = 0;
  for (;;) {
    f32x4 v = ld4_x(p);
    if (v.z == epf) return v;
    if (++g > 16) {
      if ((g & 255) == 0) {
        if (ldu_x(abortf)) return v;
        if (g > GCAP) { stu_x(abortf, 1u); vdrain(); return v; }
      }
      __builtin_amdgcn_s_sleep(2);
    }
  }
}
__device__ __forceinline__ void pollep2(const float* p0, const float* p1, float epf,
                                        unsigned* abortf, f32x4& a, f32x4& b) {
  int g = 0;
  for (;;) {
    ld4_x2(p0, p1, a, b);
    if (a.z == epf && b.z == epf) return;
    if (++g > 16) {
      if ((g & 255) == 0) {
        if (ldu_x(abortf)) return;
        if (g > GCAP) { stu_x(abortf, 1u); vdrain(); return; }
      }
      __builtin_amdgcn_s_sleep(2);
    }
  }
}
__device__ __forceinline__ void pollep3(const float* p0, const float* p1, const float* p2,
                                        float epr, float eph, unsigned* abortf,
                                        f32x4& a, f32x4& b, f32x4& c) {
  int g = 0;
  for (;;) {
    ld4_x3(p0, p1, p2, a, b, c);
    if (a.z == epr && b.z == epr && c.z == eph) return;
    if (++g > 16) {
      if ((g & 255) == 0) {
        if (ldu_x(abortf)) return;
        if (g > GCAP) { stu_x(abortf, 1u); vdrain(); return; }
      }
      __builtin_amdgcn_s_sleep(2);
    }
  }
}

// arena: hT[2][8][512] f32x4 tuples | rT[2][2][2][512] f32x4 tuples (all epochs 0)
#define HT_FLOATS (2 * 8 * 512 * 4)
#define RT_FLOATS (2 * 2 * 2 * 512 * 4)
__global__ void init_arena(float* __restrict__ arena, unsigned* __restrict__ tg) {
  const int idx = blockIdx.x * 256 + threadIdx.x;
  if (idx < HT_FLOATS + RT_FLOATS) arena[idx] = 0.f;
  if (idx < 2048) tg[idx] = 0u;
}

// Persistent 2-layer CRSD, fused epoch-tuple exchange (1 LLC RT per leg),
// Wh-partial hoisted into phase B (off the r-poll critical path).
// WGs 0..63: layer 1; 64..127: layer 2 (consumes h1(t) same tick).
// Wave wv of g owns pre-rows rb=g*16+2*wv..+1 and U-rows (k,rb),(k,rb+1).
// Tuple idx for (g,wv) = g*8+wv; consumer thread tid owns rows 2*tid,2*tid+1.
// Slots: h 8-deep (epoch-checked; h1 overwrite gated on L2 stamps >= t-7),
//        r 2-deep (phase-A r-poll + bar3 prove all own-layer reads done).
__global__ __launch_bounds__(TPB, 1)
void crsd_seq(const float* __restrict__ pwx, const float* __restrict__ Wx,
              const float* __restrict__ Wh, const float* __restrict__ Wr,
              const float* __restrict__ Uw, const float* __restrict__ bias,
              float* __restrict__ out, float* __restrict__ arena,
              unsigned* __restrict__ tg) {
  const int wg = blockIdx.x, tid = threadIdx.x;
  const int wv = tid >> 6, ln = tid & 63;
  const int layer = wg >> 6, g = wg & 63;
  const int rb = g * 16 + 2 * wv;
  const size_t MS = (size_t)DD * DD;

  float* hT0 = arena;                         // layer-1 h tuples
  float* hTL = arena + (size_t)layer * 8 * 512 * 4;
  float* rT  = arena + HT_FLOATS;
  unsigned* stamp = tg;                        // 64 L2-WG stamps, 64B-padded
  unsigned* abortf = tg + 1024;

  __shared__ __align__(16) float sh_x[DD];
  __shared__ __align__(16) float sh_h[DD];
  __shared__ __align__(16) float sh_r[2 * DD];

  const float* Whp = Wh + (size_t)layer * MS;
  const float* Wrp = Wr + (size_t)layer * 2 * MS;
  const float* Up  = Uw + (size_t)layer * 2 * MS;

  // ---- one-time weight load into registers (2 pre-rows + 4 U-rows per wave) ----
  float wh[2][16], wr[2][2][16], wx[2][16], uw[2][2][16];
#pragma unroll
  for (int ri = 0; ri < 2; ++ri) {
    const int row = rb + ri;
#pragma unroll
    for (int c = 0; c < 4; ++c) {
      const int j = 4 * ln + 256 * c;
      f32x4 a = *(const f32x4*)&Whp[(size_t)row * DD + j];
      wh[ri][4*c+0]=a.x; wh[ri][4*c+1]=a.y; wh[ri][4*c+2]=a.z; wh[ri][4*c+3]=a.w;
      f32x4 b0 = *(const f32x4*)&Wrp[(size_t)row * DD + j];
      wr[ri][0][4*c+0]=b0.x; wr[ri][0][4*c+1]=b0.y; wr[ri][0][4*c+2]=b0.z; wr[ri][0][4*c+3]=b0.w;
      f32x4 b1 = *(const f32x4*)&Wrp[MS + (size_t)row * DD + j];
      wr[ri][1][4*c+0]=b1.x; wr[ri][1][4*c+1]=b1.y; wr[ri][1][4*c+2]=b1.z; wr[ri][1][4*c+3]=b1.w;
      if (layer) {
        f32x4 xw = *(const f32x4*)&Wx[MS + (size_t)row * DD + j];
        wx[ri][4*c+0]=xw.x; wx[ri][4*c+1]=xw.y; wx[ri][4*c+2]=xw.z; wx[ri][4*c+3]=xw.w;
      } else {
        wx[ri][4*c+0]=0.f; wx[ri][4*c+1]=0.f; wx[ri][4*c+2]=0.f; wx[ri][4*c+3]=0.f;
      }
      f32x4 u0 = *(const f32x4*)&Up[(size_t)row * DD + j];
      uw[0][ri][4*c+0]=u0.x; uw[0][ri][4*c+1]=u0.y; uw[0][ri][4*c+2]=u0.z; uw[0][ri][4*c+3]=u0.w;
      f32x4 u1 = *(const f32x4*)&Up[MS + (size_t)row * DD + j];
      uw[1][ri][4*c+0]=u1.x; uw[1][ri][4*c+1]=u1.y; uw[1][ri][4*c+2]=u1.z; uw[1][ri][4*c+3]=u1.w;
    }
  }
  float bb0 = 0.f, bb1 = 0.f;
  if (layer) { bb0 = bias[DD + rb]; bb1 = bias[DD + rb + 1]; }
  float rown[2][2] = {{0.f, 0.f}, {0.f, 0.f}};
  float wp0 = 0.f, wp1 = 0.f;   // hoisted per-lane Wh*h(t-1) partials (h(-1)=0)

  for (int t = 0; t < TT; ++t) {
    const int cu = t & 7;
    const float eph = (float)(t + 1);      // epoch of tick-t publishes

    // ---- phase A: stage r(t-1) (+x=h1(t) for L2); L1 wave0 runs stamp gate ----
    if (t > 0) {
      const float epr = (float)t;          // r(t-1) epoch
      const int ps = (t - 1) & 1;
      const float* rp0 = rT + ((((size_t)(layer * 2 + 0) * 2 + ps) * 512) + tid) * 4;
      const float* rp1 = rT + ((((size_t)(layer * 2 + 1) * 2 + ps) * 512) + tid) * 4;
      f32x4 ra, rc;
      if (layer) {
        f32x4 xv;
        pollep3(rp0, rp1, hT0 + ((size_t)cu * 512 + tid) * 4, epr, eph, abortf, ra, rc, xv);
        f32x2 wxv; wxv.x = xv.x; wxv.y = xv.y;
        *(f32x2*)&sh_x[2 * tid] = wxv;
      } else {
        pollep2(rp0, rp1, epr, abortf, ra, rc);
      }
      f32x2 w0; w0.x = ra.x; w0.y = ra.y;
      f32x2 w1; w1.x = rc.x; w1.y = rc.y;
      *(f32x2*)&sh_r[2 * tid] = w0;
      *(f32x2*)&sh_r[1024 + 2 * tid] = w1;
    } else {
      sh_r[2 * tid] = 0.f; sh_r[2 * tid + 1] = 0.f;
      sh_r[1024 + 2 * tid] = 0.f; sh_r[1024 + 2 * tid + 1] = 0.f;
      if (layer) {
        f32x4 xv = pollep(hT0 + ((size_t)cu * 512 + tid) * 4, eph, abortf);
        f32x2 wxv; wxv.x = xv.x; wxv.y = xv.y;
        *(f32x2*)&sh_x[2 * tid] = wxv;
      }
    }
    if (!layer && wv == 0 && t >= 8) {
      // h1-slot reuse gate: all 64 L2 WGs consumed h1(t-8)  (stamp >= t-7)
      const unsigned tgt = (unsigned)(t - 7);
      const unsigned* sp = stamp + (ln << 4);
      int gg = 0;
      for (;;) {
        const unsigned v = ldu_x(sp);
        if (__all((int)(v >= tgt))) break;
        if (++gg > 16) {
          if ((gg & 255) == 0) {
            if (ldu_x(abortf)) break;
            if (gg > GCAP) { stu_x(abortf, 1u); vdrain(); break; }
          }
          __builtin_amdgcn_s_sleep(2);
        }
      }
    }
    float pw0 = 0.f, pw1 = 0.f;
    if (!layer && ln == 0) {
      const f32x2 p2 = *(const f32x2*)&pwx[(size_t)t * DD + rb];
      pw0 = p2.x; pw1 = p2.y;
    }
    __syncthreads();   // bar1: sh_r/sh_x staged by all threads
    if (layer && tid == 0) stu_x(stamp + (g << 4), (unsigned)(t + 1));  // consumed h1(t)

    // ---- A compute: acc = wp (hoisted Wh part) + Wr*r (+Wx*x); publish h(t) ----
    float acc0 = wp0, acc1 = wp1;
#pragma unroll
    for (int c = 0; c < 4; ++c) {
      const int j = 4 * ln + 256 * c;
      const f32x4 r0 = *(const f32x4*)&sh_r[j];
      const f32x4 r1v = *(const f32x4*)&sh_r[DD + j];
      acc0 += wr[0][0][4*c+0]*r0.x + wr[0][0][4*c+1]*r0.y + wr[0][0][4*c+2]*r0.z + wr[0][0][4*c+3]*r0.w
            + wr[0][1][4*c+0]*r1v.x + wr[0][1][4*c+1]*r1v.y + wr[0][1][4*c+2]*r1v.z + wr[0][1][4*c+3]*r1v.w;
      acc1 += wr[1][0][4*c+0]*r0.x + wr[1][0][4*c+1]*r0.y + wr[1][0][4*c+2]*r0.z + wr[1][0][4*c+3]*r0.w
            + wr[1][1][4*c+0]*r1v.x + wr[1][1][4*c+1]*r1v.y + wr[1][1][4*c+2]*r1v.z + wr[1][1][4*c+3]*r1v.w;
      if (layer) {
        const f32x4 xv = *(const f32x4*)&sh_x[j];
        acc0 += wx[0][4*c+0]*xv.x + wx[0][4*c+1]*xv.y + wx[0][4*c+2]*xv.z + wx[0][4*c+3]*xv.w;
        acc1 += wx[1][4*c+0]*xv.x + wx[1][4*c+1]*xv.y + wx[1][4*c+2]*xv.z + wx[1][4*c+3]*xv.w;
      }
    }
#pragma unroll
    for (int off = 32; off; off >>= 1) {
      acc0 += __shfl_xor(acc0, off, 64);
      acc1 += __shfl_xor(acc1, off, 64);
    }
    if (ln == 0) {
      f32x4 ht;
      ht.x = tanhf(acc0 + (layer ? bb0 : pw0));
      ht.y = tanhf(acc1 + (layer ? bb1 : pw1));
      ht.z = eph; ht.w = 0.f;
      st4_x(hTL + ((size_t)cu * 512 + g * 8 + wv) * 4, ht);   // flag+data, 1 store
      if (layer) {
        f32x2 ov; ov.x = ht.x; ov.y = ht.y;
        *(f32x2*)&out[(size_t)t * DD + rb] = ov;
      }
    }
    if (t == TT - 1) break;

    // ---- phase B: gather full h(t) (no barrier needed — phase A no longer
    //      reads sh_h; bar1 of the NEXT tick orders sh_h reuse) ----
    {
      f32x4 hv4 = pollep(hTL + ((size_t)cu * 512 + tid) * 4, eph, abortf);
      f32x2 wh2; wh2.x = hv4.x; wh2.y = hv4.y;
      *(f32x2*)&sh_h[2 * tid] = wh2;
    }
    __syncthreads();   // bar3: sh_h staged by all threads

    // U matvec (4 owned rows) -> reduce -> publish r(t) ASAP
    float ua[2][2];
#pragma unroll
    for (int k = 0; k < 2; ++k)
#pragma unroll
      for (int ri = 0; ri < 2; ++ri) {
        float a = 0.f;
#pragma unroll
        for (int c = 0; c < 4; ++c) {
          const int j = 4 * ln + 256 * c;
          const f32x4 hv = *(const f32x4*)&sh_h[j];
          a += uw[k][ri][4*c+0]*hv.x + uw[k][ri][4*c+1]*hv.y
             + uw[k][ri][4*c+2]*hv.z + uw[k][ri][4*c+3]*hv.w;
        }
#pragma unroll
        for (int off = 32; off; off >>= 1) a += __shfl_xor(a, off, 64);
        ua[k][ri] = a;
      }
    if (ln == 0) {
      const int ps = t & 1;
#pragma unroll
      for (int k = 0; k < 2; ++k) {
        rown[k][0] = 0.9f * rown[k][0] + 0.1f * tanhf(ua[k][0]);
        rown[k][1] = 0.9f * rown[k][1] + 0.1f * tanhf(ua[k][1]);
        f32x4 rt;
        rt.x = rown[k][0]; rt.y = rown[k][1]; rt.z = eph; rt.w = 0.f;
        st4_x(rT + ((((size_t)(layer * 2 + k) * 2 + ps) * 512) + g * 8 + wv) * 4, rt);
      }
    }

    // ---- hoisted Wh*h(t) partial for tick t+1 (off the critical path) ----
    wp0 = 0.f; wp1 = 0.f;
#pragma unroll
    for (int c = 0; c < 4; ++c) {
      const int j = 4 * ln + 256 * c;
      const f32x4 hv = *(const f32x4*)&sh_h[j];
      wp0 += wh[0][4*c+0]*hv.x + wh[0][4*c+1]*hv.y + wh[0][4*c+2]*hv.z + wh[0][4*c+3]*hv.w;
      wp1 += wh[1][4*c+0]*hv.x + wh[1][4*c+1]*hv.y + wh[1][4*c+2]*hv.z + wh[1][4*c+3]*hv.w;
    }
  }
}

// C[M][1024] = A[M][1024] @ W^T + bias   (W row-major [1024][1024])
__global__ __launch_bounds__(256)
void gemm_bias(const float* __restrict__ A, const float* __restrict__ W,
               const float* __restrict__ bias, float* __restrict__ C) {
  __shared__ float As[32][65];
  __shared__ float Ws[32][65];
  const int tid = threadIdx.x;
  const int bm = blockIdx.x * 64;
  const int bn = blockIdx.y * 64;
  const int ty = tid >> 4, tx = tid & 15;
  float acc[4][4] = {};
  for (int k0 = 0; k0 < DD; k0 += 32) {
#pragma unroll
    for (int p = 0; p < 2; ++p) {
      const int idx = tid + p * 256;
      const int r = idx >> 3;
      const int cf = idx & 7;
      float4 av = *(const float4*)&A[(size_t)(bm + r) * DD + k0 + cf * 4];
      As[cf*4+0][r] = av.x; As[cf*4+1][r] = av.y; As[cf*4+2][r] = av.z; As[cf*4+3][r] = av.w;
      float4 wv = *(const float4*)&W[(size_t)(bn + r) * DD + k0 + cf * 4];
      Ws[cf*4+0][r] = wv.x; Ws[cf*4+1][r] = wv.y; Ws[cf*4+2][r] = wv.z; Ws[cf*4+3][r] = wv.w;
    }
    __syncthreads();
#pragma unroll
    for (int kk = 0; kk < 32; ++kk) {
      float a[4], w[4];
#pragma unroll
      for (int e = 0; e < 4; ++e) { a[e] = As[kk][ty * 4 + e]; w[e] = Ws[kk][tx * 4 + e]; }
#pragma unroll
      for (int i = 0; i < 4; ++i)
#pragma unroll
        for (int j = 0; j < 4; ++j) acc[i][j] += a[i] * w[j];
    }
    __syncthreads();
  }
#pragma unroll
  for (int i = 0; i < 4; ++i) {
    const int m = bm + ty * 4 + i;
#pragma unroll
    for (int j = 0; j < 4; ++j) {
      const int n = bn + tx * 4 + j;
      C[(size_t)m * DD + n] = acc[i][j] + bias[n];
    }
  }
}

extern "C" void kernel_launch(void* const* d_in, const int* in_sizes, int n_in,
                              void* d_out, int out_size, void* d_ws, size_t ws_size,
                              hipStream_t stream) {
  const float* x  = (const float*)d_in[0];
  const float* Wx = (const float*)d_in[1];
  const float* Wh = (const float*)d_in[2];
  const float* Wr = (const float*)d_in[3];
  const float* U  = (const float*)d_in[4];
  const float* b  = (const float*)d_in[5];
  float* out = (float*)d_out;

  float* pwx = (float*)d_ws;                             // [T][D] fp32 = 32 MB
  float* arena = pwx + (size_t)TT * DD;                  // hT + rT tuples
  unsigned* tg = (unsigned*)(arena + HT_FLOATS + RT_FLOATS);  // stamps + abort

  hipLaunchKernelGGL(init_arena, dim3(192), dim3(256), 0, stream, arena, tg);
  hipLaunchKernelGGL(gemm_bias, dim3(TT / 64, DD / 64), dim3(256), 0, stream,
                     x, Wx, b, pwx);  // layer-1 pwx = x @ Wx1^T + b1

  const float* pwxc = pwx;
  float* arenap = arena;
  unsigned* tgp = tg;
  void* args[] = { (void*)&pwxc, (void*)&Wx, (void*)&Wh, (void*)&Wr,
                   (void*)&U, (void*)&b, (void*)&out, (void*)&arenap, (void*)&tgp };
  hipLaunchCooperativeKernel((const void*)crsd_seq, dim3(NWG), dim3(TPB),
                             args, 0, stream);
}

// Round 15
// 35173.981 us; speedup vs baseline: 1.1613x; 1.1613x over previous
//
#include <hip/hip_runtime.h>
#include <math.h>

#define TT 8192
#define DD 1024
#define LWG 64    // WGs per layer
#define NWG 128   // total
#define TPB 512   // 8 waves; each wave owns 2 pre-rows + 4 U-rows
#define GCAP (1 << 15)

typedef __attribute__((ext_vector_type(2))) float f32x2;
typedef __attribute__((ext_vector_type(4))) float f32x4;

// ---- LLC-coherent (cross-XCD) accesses: sc0 sc1 ----
__device__ __forceinline__ void vdrain() { asm volatile("s_waitcnt vmcnt(0)" ::: "memory"); }
__device__ __forceinline__ void st4_x(float* p, f32x4 v) {
  asm volatile("global_store_dwordx4 %0, %1, off sc0 sc1" :: "v"(p), "v"(v) : "memory");
}
__device__ __forceinline__ void stu_x(unsigned* p, unsigned v) {
  asm volatile("global_store_dword %0, %1, off sc0 sc1" :: "v"(p), "v"(v) : "memory");
}
__device__ __forceinline__ f32x4 ld4_x(const float* p) {
  f32x4 r;
  asm volatile("global_load_dwordx4 %0, %1, off sc0 sc1\n\ts_waitcnt vmcnt(0)"
               : "=&v"(r) : "v"(p) : "memory");
  return r;
}
__device__ __forceinline__ void ld4_x2(const float* p0, const float* p1, f32x4& a, f32x4& b) {
  asm volatile("global_load_dwordx4 %0, %2, off sc0 sc1\n\t"
               "global_load_dwordx4 %1, %3, off sc0 sc1\n\t"
               "s_waitcnt vmcnt(0)"
               : "=&v"(a), "=&v"(b) : "v"(p0), "v"(p1) : "memory");
}
__device__ __forceinline__ unsigned ldu_x(const unsigned* p) {
  unsigned r;
  asm volatile("global_load_dword %0, %1, off sc0 sc1\n\ts_waitcnt vmcnt(0)"
               : "=&v"(r) : "v"(p) : "memory");
  return r;
}

// Epoch-tuple polls (round-13 throttling: sleep(1) on alternate rounds — the
// r14 hot-poll variant congested the LLC and delayed producer stores).
__device__ __forceinline__ f32x4 pollep(const float* p, float epf, unsigned* abortf) {
  int g = 0;
  for (;;) {
    f32x4 v = ld4_x(p);
    if (v.z == epf) return v;
    if ((++g & 255) == 0) {
      if (ldu_x(abortf)) return v;
      if (g > GCAP) { stu_x(abortf, 1u); vdrain(); return v; }
    }
    if (g & 2) __builtin_amdgcn_s_sleep(1);
  }
}
__device__ __forceinline__ void pollep2(const float* p0, const float* p1, float epf,
                                        unsigned* abortf, f32x4& a, f32x4& b) {
  int g = 0;
  for (;;) {
    ld4_x2(p0, p1, a, b);
    if (a.z == epf && b.z == epf) return;
    if ((++g & 255) == 0) {
      if (ldu_x(abortf)) return;
      if (g > GCAP) { stu_x(abortf, 1u); vdrain(); return; }
    }
    if (g & 2) __builtin_amdgcn_s_sleep(1);
  }
}

// arena: hT[2][8][512] f32x4 tuples | rT[2][2][2][512] f32x4 tuples (all epochs 0)
#define HT_FLOATS (2 * 8 * 512 * 4)
#define RT_FLOATS (2 * 2 * 2 * 512 * 4)
__global__ void init_arena(float* __restrict__ arena, unsigned* __restrict__ tg) {
  const int idx = blockIdx.x * 256 + threadIdx.x;
  if (idx < HT_FLOATS + RT_FLOATS) arena[idx] = 0.f;
  if (idx < 2048) tg[idx] = 0u;
}

// Persistent 2-layer CRSD, fused epoch-tuple exchange (1 LLC RT per leg).
// Structure = round 14 (Wh-partial hoisted to phase B, 2 barriers/tick);
// poll discipline = round 13 (throttled, sequential). Correctness of the
// structure proven by r14's pass; r13 proves the poll discipline's speed.
// WGs 0..63: layer 1; 64..127: layer 2 (consumes h1(t) same tick).
// Wave wv of g owns pre-rows rb=g*16+2*wv..+1 and U-rows (k,rb),(k,rb+1).
// Slots: h 8-deep (epoch-checked; h1 overwrite gated on L2 stamps >= t-7),
//        r 2-deep (phase-A r-poll + bar3 prove all own-layer reads done).
__global__ __launch_bounds__(TPB, 1)
void crsd_seq(const float* __restrict__ pwx, const float* __restrict__ Wx,
              const float* __restrict__ Wh, const float* __restrict__ Wr,
              const float* __restrict__ Uw, const float* __restrict__ bias,
              float* __restrict__ out, float* __restrict__ arena,
              unsigned* __restrict__ tg) {
  const int wg = blockIdx.x, tid = threadIdx.x;
  const int wv = tid >> 6, ln = tid & 63;
  const int layer = wg >> 6, g = wg & 63;
  const int rb = g * 16 + 2 * wv;
  const size_t MS = (size_t)DD * DD;

  float* hT0 = arena;                         // layer-1 h tuples
  float* hTL = arena + (size_t)layer * 8 * 512 * 4;
  float* rT  = arena + HT_FLOATS;
  unsigned* stamp = tg;                        // 64 L2-WG stamps, 64B-padded
  unsigned* abortf = tg + 1024;

  __shared__ __align__(16) float sh_x[DD];
  __shared__ __align__(16) float sh_h[DD];
  __shared__ __align__(16) float sh_r[2 * DD];

  const float* Whp = Wh + (size_t)layer * MS;
  const float* Wrp = Wr + (size_t)layer * 2 * MS;
  const float* Up  = Uw + (size_t)layer * 2 * MS;

  // ---- one-time weight load into registers (2 pre-rows + 4 U-rows per wave) ----
  float wh[2][16], wr[2][2][16], wx[2][16], uw[2][2][16];
#pragma unroll
  for (int ri = 0; ri < 2; ++ri) {
    const int row = rb + ri;
#pragma unroll
    for (int c = 0; c < 4; ++c) {
      const int j = 4 * ln + 256 * c;
      f32x4 a = *(const f32x4*)&Whp[(size_t)row * DD + j];
      wh[ri][4*c+0]=a.x; wh[ri][4*c+1]=a.y; wh[ri][4*c+2]=a.z; wh[ri][4*c+3]=a.w;
      f32x4 b0 = *(const f32x4*)&Wrp[(size_t)row * DD + j];
      wr[ri][0][4*c+0]=b0.x; wr[ri][0][4*c+1]=b0.y; wr[ri][0][4*c+2]=b0.z; wr[ri][0][4*c+3]=b0.w;
      f32x4 b1 = *(const f32x4*)&Wrp[MS + (size_t)row * DD + j];
      wr[ri][1][4*c+0]=b1.x; wr[ri][1][4*c+1]=b1.y; wr[ri][1][4*c+2]=b1.z; wr[ri][1][4*c+3]=b1.w;
      if (layer) {
        f32x4 xw = *(const f32x4*)&Wx[MS + (size_t)row * DD + j];
        wx[ri][4*c+0]=xw.x; wx[ri][4*c+1]=xw.y; wx[ri][4*c+2]=xw.z; wx[ri][4*c+3]=xw.w;
      } else {
        wx[ri][4*c+0]=0.f; wx[ri][4*c+1]=0.f; wx[ri][4*c+2]=0.f; wx[ri][4*c+3]=0.f;
      }
      f32x4 u0 = *(const f32x4*)&Up[(size_t)row * DD + j];
      uw[0][ri][4*c+0]=u0.x; uw[0][ri][4*c+1]=u0.y; uw[0][ri][4*c+2]=u0.z; uw[0][ri][4*c+3]=u0.w;
      f32x4 u1 = *(const f32x4*)&Up[MS + (size_t)row * DD + j];
      uw[1][ri][4*c+0]=u1.x; uw[1][ri][4*c+1]=u1.y; uw[1][ri][4*c+2]=u1.z; uw[1][ri][4*c+3]=u1.w;
    }
  }
  float bb0 = 0.f, bb1 = 0.f;
  if (layer) { bb0 = bias[DD + rb]; bb1 = bias[DD + rb + 1]; }
  float rown[2][2] = {{0.f, 0.f}, {0.f, 0.f}};
  float wp0 = 0.f, wp1 = 0.f;   // hoisted per-lane Wh*h(t-1) partials (h(-1)=0)

  for (int t = 0; t < TT; ++t) {
    const int cu = t & 7;
    const float eph = (float)(t + 1);      // epoch of tick-t publishes

    // ---- phase A: stage r(t-1) (+x=h1(t) for L2); L1 wave0 runs stamp gate ----
    if (t > 0) {
      const float epr = (float)t;          // r(t-1) epoch
      const int ps = (t - 1) & 1;
      f32x4 ra, rc;
      pollep2(rT + ((((size_t)(layer * 2 + 0) * 2 + ps) * 512) + tid) * 4,
              rT + ((((size_t)(layer * 2 + 1) * 2 + ps) * 512) + tid) * 4,
              epr, abortf, ra, rc);
      f32x2 w0; w0.x = ra.x; w0.y = ra.y;
      f32x2 w1; w1.x = rc.x; w1.y = rc.y;
      *(f32x2*)&sh_r[2 * tid] = w0;
      *(f32x2*)&sh_r[1024 + 2 * tid] = w1;
    } else {
      sh_r[2 * tid] = 0.f; sh_r[2 * tid + 1] = 0.f;
      sh_r[1024 + 2 * tid] = 0.f; sh_r[1024 + 2 * tid + 1] = 0.f;
    }
    if (layer) {
      f32x4 xv = pollep(hT0 + ((size_t)cu * 512 + tid) * 4, eph, abortf);
      f32x2 wxv; wxv.x = xv.x; wxv.y = xv.y;
      *(f32x2*)&sh_x[2 * tid] = wxv;
    } else if (wv == 0 && t >= 8) {
      // h1-slot reuse gate: all 64 L2 WGs consumed h1(t-8)  (stamp >= t-7)
      const unsigned tgt = (unsigned)(t - 7);
      const unsigned* sp = stamp + (ln << 4);
      int gg = 0;
      for (;;) {
        const unsigned v = ldu_x(sp);
        if (__all((int)(v >= tgt))) break;
        if ((++gg & 255) == 0) {
          if (ldu_x(abortf)) break;
          if (gg > GCAP) { stu_x(abortf, 1u); vdrain(); break; }
        }
        __builtin_amdgcn_s_sleep(1);
      }
    }
    float px0 = 0.f, px1 = 0.f;
    if (!layer && ln == 0) {
      const f32x2 p2 = *(const f32x2*)&pwx[(size_t)t * DD + rb];
      px0 = p2.x; px1 = p2.y;
    }
    __syncthreads();   // bar1: sh_r/sh_x staged by all threads
    if (layer && tid == 0) stu_x(stamp + (g << 4), (unsigned)(t + 1));  // consumed h1(t)

    // ---- A compute: acc = wp (hoisted Wh part) + Wr*r (+Wx*x); publish h(t) ----
    float acc0 = wp0, acc1 = wp1;
#pragma unroll
    for (int c = 0; c < 4; ++c) {
      const int j = 4 * ln + 256 * c;
      const f32x4 r0 = *(const f32x4*)&sh_r[j];
      const f32x4 r1v = *(const f32x4*)&sh_r[DD + j];
      acc0 += wr[0][0][4*c+0]*r0.x + wr[0][0][4*c+1]*r0.y + wr[0][0][4*c+2]*r0.z + wr[0][0][4*c+3]*r0.w
            + wr[0][1][4*c+0]*r1v.x + wr[0][1][4*c+1]*r1v.y + wr[0][1][4*c+2]*r1v.z + wr[0][1][4*c+3]*r1v.w;
      acc1 += wr[1][0][4*c+0]*r0.x + wr[1][0][4*c+1]*r0.y + wr[1][0][4*c+2]*r0.z + wr[1][0][4*c+3]*r0.w
            + wr[1][1][4*c+0]*r1v.x + wr[1][1][4*c+1]*r1v.y + wr[1][1][4*c+2]*r1v.z + wr[1][1][4*c+3]*r1v.w;
      if (layer) {
        const f32x4 xv = *(const f32x4*)&sh_x[j];
        acc0 += wx[0][4*c+0]*xv.x + wx[0][4*c+1]*xv.y + wx[0][4*c+2]*xv.z + wx[0][4*c+3]*xv.w;
        acc1 += wx[1][4*c+0]*xv.x + wx[1][4*c+1]*xv.y + wx[1][4*c+2]*xv.z + wx[1][4*c+3]*xv.w;
      }
    }
#pragma unroll
    for (int off = 32; off; off >>= 1) {
      acc0 += __shfl_xor(acc0, off, 64);
      acc1 += __shfl_xor(acc1, off, 64);
    }
    if (ln == 0) {
      f32x4 ht;
      ht.x = tanhf(acc0 + (layer ? bb0 : px0));
      ht.y = tanhf(acc1 + (layer ? bb1 : px1));
      ht.z = eph; ht.w = 0.f;
      st4_x(hTL + ((size_t)cu * 512 + g * 8 + wv) * 4, ht);   // flag+data, 1 store
      if (layer) {
        f32x2 ov; ov.x = ht.x; ov.y = ht.y;
        *(f32x2*)&out[(size_t)t * DD + rb] = ov;
      }
    }
    if (t == TT - 1) break;

    // ---- phase B: gather full h(t) (no barrier needed — phase A no longer
    //      reads sh_h; bar1 of the NEXT tick orders sh_h reuse) ----
    {
      f32x4 hv4 = pollep(hTL + ((size_t)cu * 512 + tid) * 4, eph, abortf);
      f32x2 wh2; wh2.x = hv4.x; wh2.y = hv4.y;
      *(f32x2*)&sh_h[2 * tid] = wh2;
    }
    __syncthreads();   // bar3: sh_h staged by all threads

    // U matvec (4 owned rows) -> reduce -> publish r(t) ASAP
    float ua[2][2];
#pragma unroll
    for (int k = 0; k < 2; ++k)
#pragma unroll
      for (int ri = 0; ri < 2; ++ri) {
        float a = 0.f;
#pragma unroll
        for (int c = 0; c < 4; ++c) {
          const int j = 4 * ln + 256 * c;
          const f32x4 hv = *(const f32x4*)&sh_h[j];
          a += uw[k][ri][4*c+0]*hv.x + uw[k][ri][4*c+1]*hv.y
             + uw[k][ri][4*c+2]*hv.z + uw[k][ri][4*c+3]*hv.w;
        }
#pragma unroll
        for (int off = 32; off; off >>= 1) a += __shfl_xor(a, off, 64);
        ua[k][ri] = a;
      }
    if (ln == 0) {
      const int ps = t & 1;
#pragma unroll
      for (int k = 0; k < 2; ++k) {
        rown[k][0] = 0.9f * rown[k][0] + 0.1f * tanhf(ua[k][0]);
        rown[k][1] = 0.9f * rown[k][1] + 0.1f * tanhf(ua[k][1]);
        f32x4 rt;
        rt.x = rown[k][0]; rt.y = rown[k][1]; rt.z = eph; rt.w = 0.f;
        st4_x(rT + ((((size_t)(layer * 2 + k) * 2 + ps) * 512) + g * 8 + wv) * 4, rt);
      }
    }

    // ---- hoisted Wh*h(t) partial for tick t+1 (off the critical path) ----
    wp0 = 0.f; wp1 = 0.f;
#pragma unroll
    for (int c = 0; c < 4; ++c) {
      const int j = 4 * ln + 256 * c;
      const f32x4 hv = *(const f32x4*)&sh_h[j];
      wp0 += wh[0][4*c+0]*hv.x + wh[0][4*c+1]*hv.y + wh[0][4*c+2]*hv.z + wh[0][4*c+3]*hv.w;
      wp1 += wh[1][4*c+0]*hv.x + wh[1][4*c+1]*hv.y + wh[1][4*c+2]*hv.z + wh[1][4*c+3]*hv.w;
    }
  }
}

// C[M][1024] = A[M][1024] @ W^T + bias   (W row-major [1024][1024])
__global__ __launch_bounds__(256)
void gemm_bias(const float* __restrict__ A, const float* __restrict__ W,
               const float* __restrict__ bias, float* __restrict__ C) {
  __shared__ float As[32][65];
  __shared__ float Ws[32][65];
  const int tid = threadIdx.x;
  const int bm = blockIdx.x * 64;
  const int bn = blockIdx.y * 64;
  const int ty = tid >> 4, tx = tid & 15;
  float acc[4][4] = {};
  for (int k0 = 0; k0 < DD; k0 += 32) {
#pragma unroll
    for (int p = 0; p < 2; ++p) {
      const int idx = tid + p * 256;
      const int r = idx >> 3;
      const int cf = idx & 7;
      float4 av = *(const float4*)&A[(size_t)(bm + r) * DD + k0 + cf * 4];
      As[cf*4+0][r] = av.x; As[cf*4+1][r] = av.y; As[cf*4+2][r] = av.z; As[cf*4+3][r] = av.w;
      float4 wv = *(const float4*)&W[(size_t)(bn + r) * DD + k0 + cf * 4];
      Ws[cf*4+0][r] = wv.x; Ws[cf*4+1][r] = wv.y; Ws[cf*4+2][r] = wv.z; Ws[cf*4+3][r] = wv.w;
    }
    __syncthreads();
#pragma unroll
    for (int kk = 0; kk < 32; ++kk) {
      float a[4], w[4];
#pragma unroll
      for (int e = 0; e < 4; ++e) { a[e] = As[kk][ty * 4 + e]; w[e] = Ws[kk][tx * 4 + e]; }
#pragma unroll
      for (int i = 0; i < 4; ++i)
#pragma unroll
        for (int j = 0; j < 4; ++j) acc[i][j] += a[i] * w[j];
    }
    __syncthreads();
  }
#pragma unroll
  for (int i = 0; i < 4; ++i) {
    const int m = bm + ty * 4 + i;
#pragma unroll
    for (int j = 0; j < 4; ++j) {
      const int n = bn + tx * 4 + j;
      C[(size_t)m * DD + n] = acc[i][j] + bias[n];
    }
  }
}

extern "C" void kernel_launch(void* const* d_in, const int* in_sizes, int n_in,
                              void* d_out, int out_size, void* d_ws, size_t ws_size,
                              hipStream_t stream) {
  const float* x  = (const float*)d_in[0];
  const float* Wx = (const float*)d_in[1];
  const float* Wh = (const float*)d_in[2];
  const float* Wr = (const float*)d_in[3];
  const float* U  = (const float*)d_in[4];
  const float* b  = (const float*)d_in[5];
  float* out = (float*)d_out;

  float* pwx = (float*)d_ws;                             // [T][D] fp32 = 32 MB
  float* arena = pwx + (size_t)TT * DD;                  // hT + rT tuples
  unsigned* tg = (unsigned*)(arena + HT_FLOATS + RT_FLOATS);  // stamps + abort

  hipLaunchKernelGGL(init_arena, dim3(192), dim3(256), 0, stream, arena, tg);
  hipLaunchKernelGGL(gemm_bias, dim3(TT / 64, DD / 64), dim3(256), 0, stream,
                     x, Wx, b, pwx);  // layer-1 pwx = x @ Wx1^T + b1

  const float* pwxc = pwx;
  float* arenap = arena;
  unsigned* tgp = tg;
  void* args[] = { (void*)&pwxc, (void*)&Wx, (void*)&Wh, (void*)&Wr,
                   (void*)&U, (void*)&b, (void*)&out, (void*)&arenap, (void*)&tgp };
  hipLaunchCooperativeKernel((const void*)crsd_seq, dim3(NWG), dim3(TPB),
                             args, 0, stream);
}